// Round 1
// baseline (377.725 us; speedup 1.0000x reference)
//
#include <hip/hip_runtime.h>

// Problem: B=4, H=8, S=2048, D=64
// out  = [B*H*S*D]  floats   (first 4,194,304 of d_out)
// p    = [B*H*S*S]  floats   (next 134,217,728 of d_out)
#define NB 4
#define NH 8
#define NS 2048
#define ND 64
#define NBH (NB * NH)

constexpr int TQ = 128;   // q rows per block
constexpr int TK = 128;   // k cols per tile

// ---------------------------------------------------------------------------
// Kernel 1: fp32 QK^T with per-row masked top-2 logit tracking.
// Writes zeros over the whole p tile, then (for "clean" = effectively one-hot
// rows) writes p[row][argmax]=1.0 and out[row]=V[argmax].
// Non-clean rows (ties / fully-masked) are appended to a ws list for kernel 2.
// ---------------------------------------------------------------------------
__global__ __launch_bounds__(256, 2)
void qk_argmax_kernel(const float* __restrict__ Q,
                      const float* __restrict__ K,
                      const float* __restrict__ V,
                      const int*   __restrict__ mask,
                      float* __restrict__ outp,
                      float* __restrict__ p,
                      int* __restrict__ wsl, int wscap)
{
    __shared__ float qs[TQ * ND];   // XOR-swizzled: f4 idx = row*16 + (c4 ^ (row>>3))
    __shared__ float ks[TK * ND];
    __shared__ int   argb[TQ];

    const int t  = threadIdx.x;
    const int tx = t & 15;          // key group (8 keys each)
    const int ty = t >> 4;          // row group (8 rows each), 0..15
    const int bh = blockIdx.y;      // 0..31
    const int b  = bh >> 3;
    const int q0 = blockIdx.x * TQ;

    const float* Qb = Q + ((size_t)bh * NS + q0) * ND;
    const float* Kb = K + (size_t)bh * NS * ND;
    const float* Vb = V + (size_t)bh * NS * ND;
    const int*   mb = mask + (size_t)b * NS * NS + (size_t)q0 * NS;
    float*       pb = p + ((size_t)bh * NS + q0) * NS;

    float4* qs4 = (float4*)qs;
    float4* ks4 = (float4*)ks;

    // stage Q tile (swizzled so compute-phase ds_read_b128 is ~conflict-free)
    #pragma unroll
    for (int s = 0; s < 8; ++s) {
        int f = t + 256 * s;            // 0..2047 float4s
        int row = f >> 4, c4 = f & 15;
        qs4[row * 16 + (c4 ^ (row >> 3))] = *(const float4*)(Qb + row * ND + c4 * 4);
    }

    float rm1[8], rm2[8];
    int   ri1[8];
    #pragma unroll
    for (int j = 0; j < 8; ++j) { rm1[j] = -1e30f; rm2[j] = -1e30f; ri1[j] = 0; }

    for (int kt = 0; kt < NS / TK; ++kt) {
        __syncthreads();
        #pragma unroll
        for (int s = 0; s < 8; ++s) {
            int f = t + 256 * s;
            int row = f >> 4, c4 = f & 15;
            ks4[row * 16 + (c4 ^ (row >> 3))] =
                *(const float4*)(Kb + (size_t)(kt * TK + row) * ND + c4 * 4);
        }
        __syncthreads();

        float acc[8][8];
        #pragma unroll
        for (int j = 0; j < 8; ++j)
            #pragma unroll
            for (int i = 0; i < 8; ++i) acc[j][i] = 0.f;

        #pragma unroll 2
        for (int dd = 0; dd < 16; ++dd) {
            float4 qv[8], kv[8];
            #pragma unroll
            for (int j = 0; j < 8; ++j) qv[j] = qs4[(ty * 8 + j) * 16 + (dd ^ ty)];
            #pragma unroll
            for (int i = 0; i < 8; ++i) kv[i] = ks4[(tx * 8 + i) * 16 + (dd ^ tx)];
            #pragma unroll
            for (int j = 0; j < 8; ++j)
                #pragma unroll
                for (int i = 0; i < 8; ++i) {
                    acc[j][i] += qv[j].x * kv[i].x;
                    acc[j][i] += qv[j].y * kv[i].y;
                    acc[j][i] += qv[j].z * kv[i].z;
                    acc[j][i] += qv[j].w * kv[i].w;
                }
        }

        // mask, track top-2 logits, zero-fill this p tile
        #pragma unroll
        for (int j = 0; j < 8; ++j) {
            int qrow = ty * 8 + j;
            const int* mrow = mb + (size_t)qrow * NS + kt * TK + tx * 8;
            int4 ma  = *(const int4*)(mrow);
            int4 mbv = *(const int4*)(mrow + 4);
            float l[8];
            l[0] = ma.x  ? acc[j][0] : -1e30f;
            l[1] = ma.y  ? acc[j][1] : -1e30f;
            l[2] = ma.z  ? acc[j][2] : -1e30f;
            l[3] = ma.w  ? acc[j][3] : -1e30f;
            l[4] = mbv.x ? acc[j][4] : -1e30f;
            l[5] = mbv.y ? acc[j][5] : -1e30f;
            l[6] = mbv.z ? acc[j][6] : -1e30f;
            l[7] = mbv.w ? acc[j][7] : -1e30f;

            float a1 = l[0]; int ai = 0; float a2 = -1e30f;
            #pragma unroll
            for (int i = 1; i < 8; ++i) {
                if (l[i] > a1) { a2 = a1; a1 = l[i]; ai = i; }
                else           { a2 = fmaxf(a2, l[i]); }
            }
            int gkey = kt * TK + tx * 8 + ai;
            if (a1 > rm1[j]) { rm2[j] = fmaxf(rm1[j], a2); rm1[j] = a1; ri1[j] = gkey; }
            else             { rm2[j] = fmaxf(rm2[j], fmaxf(a1, -1e30f)); }

            // zero-fill p tile (coalesced: 16 lanes x 16B contiguous per half)
            float4 z = make_float4(0.f, 0.f, 0.f, 0.f);
            *(float4*)(pb + (size_t)qrow * NS + kt * TK + tx * 4)      = z;
            *(float4*)(pb + (size_t)qrow * NS + kt * TK + 64 + tx * 4) = z;
        }
    }

    // reduce top-2 across the 16 tx lanes (overlap-safe merge via index compare)
    #pragma unroll
    for (int j = 0; j < 8; ++j) {
        float m1 = rm1[j], m2 = rm2[j];
        int   i1 = ri1[j];
        #pragma unroll
        for (int d = 1; d < 16; d <<= 1) {
            float om1 = __shfl_xor(m1, d, 64);
            float om2 = __shfl_xor(m2, d, 64);
            int   oi1 = __shfl_xor(i1, d, 64);
            float nm1; int ni1; float nm2;
            if (om1 > m1)      { nm1 = om1; ni1 = oi1; nm2 = fmaxf(om2, m1); }
            else if (om1 < m1) { nm1 = m1;  ni1 = i1;  nm2 = fmaxf(m2, om1); }
            else { // equal tops
                nm1 = m1; ni1 = i1;
                nm2 = (oi1 == i1) ? fmaxf(m2, om2) : m1; // distinct-key tie -> gap 0
            }
            m1 = nm1; i1 = ni1; m2 = nm2;
        }
        if (tx == 0) {
            int qrow = ty * 8 + j;
            float s1 = __expf(m1) * 0.125f;
            float s2 = __expf(m2) * 0.125f;
            // clean: residual softmax mass <= 2047*e^-15 ~ 6e-4 << 0.0975
            bool clean = (m1 > -1e29f) && (s1 < 1e38f) && (s1 - s2 > 15.0f);
            if (clean) argb[qrow] = i1;
            else if (wscap > 0) {
                argb[qrow] = -1;
                int idx = atomicAdd(wsl, 1);
                if (idx < wscap) wsl[1 + idx] = bh * NS + q0 + qrow;
            } else {
                argb[qrow] = i1;   // no workspace: best-effort fallback
            }
        }
    }
    __syncthreads();   // drains all zero-stores (vmcnt(0) before s_barrier)

    // emit one-hot + out = V[argmax] for clean rows
    #pragma unroll
    for (int s = 0; s < 8; ++s) {
        int task = t + 256 * s;          // 2048 tasks = 128 rows x 16 float4s
        int row = task >> 4, c4 = task & 15;
        int a = argb[row];
        if (a >= 0) {
            *(float4*)(outp + ((size_t)bh * NS + q0 + row) * ND + c4 * 4) =
                *(const float4*)(Vb + (size_t)a * ND + c4 * 4);
            if (c4 == 0) pb[(size_t)row * NS + a] = 1.0f;
        }
    }
}

// ---------------------------------------------------------------------------
// Kernel 2: exact reference softmax for listed (non-one-hot) rows.
// Mirrors the reference numerics: score = mask ? exp(l)/8 : -1e9; stable
// softmax; out = sum p*V. Expected list length: 0.
// ---------------------------------------------------------------------------
__global__ __launch_bounds__(256)
void slow_rows_kernel(const float* __restrict__ Q, const float* __restrict__ K,
                      const float* __restrict__ V, const int* __restrict__ mask,
                      float* __restrict__ outp, float* __restrict__ p,
                      const int* __restrict__ wsl, int wscap)
{
    __shared__ float qr[ND];
    __shared__ float redm[4], redz[4];
    __shared__ float ol[ND];
    int n = wsl[0];
    if (n > wscap) n = wscap;
    const int t = threadIdx.x;
    const int lane = t & 63, w = t >> 6;

    for (int ii = blockIdx.x; ii < n; ii += gridDim.x) {
        int row = wsl[1 + ii];           // global row = bh*NS + q
        int bh = row >> 11, q = row & (NS - 1), b = bh >> 3;
        const float* Qr = Q + (size_t)row * ND;
        const float* Kb = K + (size_t)bh * NS * ND;
        const float* Vb = V + (size_t)bh * NS * ND;
        const int*   mr = mask + (size_t)b * NS * NS + (size_t)q * NS;

        __syncthreads();                 // protect LDS reuse across iterations
        if (t < 16) ((float4*)qr)[t] = ((const float4*)Qr)[t];
        if (t < ND) ol[t] = 0.f;
        __syncthreads();

        float sc[8];
        int k0 = t * 8;
        #pragma unroll
        for (int i = 0; i < 8; ++i) {
            const float* kr = Kb + (size_t)(k0 + i) * ND;
            float a = 0.f;
            for (int d = 0; d < ND; d += 4) {
                float4 kv = *(const float4*)(kr + d);
                a += qr[d] * kv.x; a += qr[d + 1] * kv.y;
                a += qr[d + 2] * kv.z; a += qr[d + 3] * kv.w;
            }
            sc[i] = mr[k0 + i] ? __expf(a) * 0.125f : -1e9f;
        }
        float m = sc[0];
        #pragma unroll
        for (int i = 1; i < 8; ++i) m = fmaxf(m, sc[i]);
        #pragma unroll
        for (int d = 1; d < 64; d <<= 1) m = fmaxf(m, __shfl_xor(m, d, 64));
        if (lane == 0) redm[w] = m;
        __syncthreads();
        m = fmaxf(fmaxf(redm[0], redm[1]), fmaxf(redm[2], redm[3]));

        float e[8]; float z = 0.f;
        #pragma unroll
        for (int i = 0; i < 8; ++i) { e[i] = __expf(sc[i] - m); z += e[i]; }
        #pragma unroll
        for (int d = 1; d < 64; d <<= 1) z += __shfl_xor(z, d, 64);
        if (lane == 0) redz[w] = z;
        __syncthreads();
        float Z = redz[0] + redz[1] + redz[2] + redz[3];
        float inv = 1.f / Z;

        float* pr = p + (size_t)row * NS + k0;
        float4 o0, o1;
        o0.x = e[0] * inv; o0.y = e[1] * inv; o0.z = e[2] * inv; o0.w = e[3] * inv;
        o1.x = e[4] * inv; o1.y = e[5] * inv; o1.z = e[6] * inv; o1.w = e[7] * inv;
        *(float4*)pr = o0; *(float4*)(pr + 4) = o1;

        #pragma unroll
        for (int i = 0; i < 8; ++i) {
            float pv = e[i] * inv;
            if (pv > 0.f) {
                const float* vr = Vb + (size_t)(k0 + i) * ND;
                for (int d = 0; d < ND; ++d) atomicAdd(&ol[d], pv * vr[d]);
            }
        }
        __syncthreads();
        if (t < ND) outp[(size_t)row * ND + t] = ol[t];
    }
}

extern "C" void kernel_launch(void* const* d_in, const int* in_sizes, int n_in,
                              void* d_out, int out_size, void* d_ws, size_t ws_size,
                              hipStream_t stream)
{
    const float* Q    = (const float*)d_in[0];
    const float* K    = (const float*)d_in[1];
    const float* V    = (const float*)d_in[2];
    const int*   mask = (const int*)d_in[3];
    float* outp = (float*)d_out;
    float* p    = outp + (size_t)NBH * NS * ND;   // p_attn after out
    int*   wsl  = (int*)d_ws;
    int wscap = (ws_size >= 8) ? (int)(ws_size / 4 - 1) : 0;
    if (wscap > 65536) wscap = 65536;

    if (wscap > 0) hipMemsetAsync(d_ws, 0, 4, stream);   // reset non-clean count

    dim3 grid(NS / TQ, NBH);  // (16, 32)
    qk_argmax_kernel<<<grid, 256, 0, stream>>>(Q, K, V, mask, outp, p, wsl, wscap);
    if (wscap > 0)
        slow_rows_kernel<<<dim3(128), 256, 0, stream>>>(Q, K, V, mask, outp, p, wsl, wscap);
}